// Round 1
// baseline (1053.245 us; speedup 1.0000x reference)
//
#include <hip/hip_runtime.h>
#include <hip/hip_bf16.h>

// PSN: quantize latents (16384 x 256) against codebook (8192 x 256).
// Outputs (flat f32): st[16384*256], loss[1], inds_noisy[16384] (as float).

namespace {
constexpr int N_ROWS  = 16384;   // B*E
constexpr int K_CODES = 8192;
constexpr int C_DIM   = 256;

constexpr int BM = 128;          // rows per block
constexpr int BN = 256;          // codes per k-tile
constexpr int BC = 16;           // C chunk
constexpr int KSPLIT = 4;        // grid = 128 row-blocks * 4 = 512 blocks (2/CU)
constexpr int KRANGE = K_CODES / KSPLIT;  // 2048
constexpr int SX = BM + 4;       // 132 (pad: staging writes 2-way, reads conflict-free)
constexpr int SW = BN + 4;       // 260
}

__device__ __forceinline__ unsigned int f2key(float f) {
    // monotone f32 -> u32 map (no NaNs in this problem)
    unsigned int u = __float_as_uint(f);
    return (u & 0x80000000u) ? ~u : (u | 0x80000000u);
}

extern "C" __global__ void wnorm_kernel(const float* __restrict__ cbk,
                                        float* __restrict__ wnorm) {
    const int k = blockIdx.x * 4 + (threadIdx.x >> 6);   // one wave per code row
    const int lane = threadIdx.x & 63;
    float4 v = reinterpret_cast<const float4*>(cbk + (size_t)k * C_DIM)[lane];
    float s = v.x * v.x + v.y * v.y + v.z * v.z + v.w * v.w;
    #pragma unroll
    for (int m = 32; m; m >>= 1) s += __shfl_xor(s, m, 64);
    if (lane == 0) wnorm[k] = s;
}

extern "C" __global__ void __launch_bounds__(256, 2)
argmin_kernel(const float* __restrict__ lat, const float* __restrict__ cbk,
              const float* __restrict__ wnorm,
              unsigned long long* __restrict__ keys) {
    __shared__ float xs[BC][SX];   // transposed: xs[c][row]
    __shared__ float ws[BC][SW];   // transposed: ws[c][code]
    const int tid = threadIdx.x;
    const int tx = tid & 15;
    const int ty = tid >> 4;
    const int rb  = blockIdx.x & (N_ROWS / BM - 1);  // 0..127
    const int ksp = blockIdx.x >> 7;                 // 0..KSPLIT-1
    const int r0 = rb * BM;

    unsigned long long best[8];
    #pragma unroll
    for (int r = 0; r < 8; ++r) best[r] = ~0ull;

    const int srow = tid >> 1;         // 0..127 (x staging)
    const int scol = (tid & 1) * 8;    // 0 or 8

    for (int kt = 0; kt < KRANGE / BN; ++kt) {
        const int k0 = ksp * KRANGE + kt * BN;
        float acc[8][16];
        #pragma unroll
        for (int r = 0; r < 8; ++r)
            #pragma unroll
            for (int n = 0; n < 16; ++n) acc[r][n] = 0.0f;

        for (int cB = 0; cB < C_DIM / BC; ++cB) {
            const int c0 = cB * BC;
            __syncthreads();
            {
                // stage x tile: 128 rows x 16 c, 2 float4 per thread
                const float* xp = lat + (size_t)(r0 + srow) * C_DIM + c0 + scol;
                float4 a0 = *reinterpret_cast<const float4*>(xp);
                float4 a1 = *reinterpret_cast<const float4*>(xp + 4);
                xs[scol + 0][srow] = a0.x; xs[scol + 1][srow] = a0.y;
                xs[scol + 2][srow] = a0.z; xs[scol + 3][srow] = a0.w;
                xs[scol + 4][srow] = a1.x; xs[scol + 5][srow] = a1.y;
                xs[scol + 6][srow] = a1.z; xs[scol + 7][srow] = a1.w;
                // stage w tile: 256 codes x 16 c, one code row per thread
                const float* wp = cbk + (size_t)(k0 + tid) * C_DIM + c0;
                float4 w0 = *reinterpret_cast<const float4*>(wp + 0);
                float4 w1 = *reinterpret_cast<const float4*>(wp + 4);
                float4 w2 = *reinterpret_cast<const float4*>(wp + 8);
                float4 w3 = *reinterpret_cast<const float4*>(wp + 12);
                ws[0][tid]  = w0.x; ws[1][tid]  = w0.y; ws[2][tid]  = w0.z; ws[3][tid]  = w0.w;
                ws[4][tid]  = w1.x; ws[5][tid]  = w1.y; ws[6][tid]  = w1.z; ws[7][tid]  = w1.w;
                ws[8][tid]  = w2.x; ws[9][tid]  = w2.y; ws[10][tid] = w2.z; ws[11][tid] = w2.w;
                ws[12][tid] = w3.x; ws[13][tid] = w3.y; ws[14][tid] = w3.z; ws[15][tid] = w3.w;
            }
            __syncthreads();
            for (int cc = 0; cc < BC; ++cc) {
                float xr[8], wv[16];
                *reinterpret_cast<float4*>(&xr[0]) =
                    *reinterpret_cast<const float4*>(&xs[cc][ty * 8]);
                *reinterpret_cast<float4*>(&xr[4]) =
                    *reinterpret_cast<const float4*>(&xs[cc][ty * 8 + 4]);
                #pragma unroll
                for (int q = 0; q < 4; ++q)
                    *reinterpret_cast<float4*>(&wv[q * 4]) =
                        *reinterpret_cast<const float4*>(&ws[cc][q * 64 + tx * 4]);
                #pragma unroll
                for (int r = 0; r < 8; ++r)
                    #pragma unroll
                    for (int n = 0; n < 16; ++n)
                        acc[r][n] = fmaf(xr[r], wv[n], acc[r][n]);
            }
        }
        // scores + running argmin (packed u64: ties -> lowest index, matches numpy)
        #pragma unroll
        for (int q = 0; q < 4; ++q) {
            #pragma unroll
            for (int j = 0; j < 4; ++j) {
                const int kc = k0 + q * 64 + tx * 4 + j;
                const float wn = wnorm[kc];
                const int n = q * 4 + j;
                #pragma unroll
                for (int r = 0; r < 8; ++r) {
                    float s = fmaf(-2.0f, acc[r][n], wn);
                    unsigned long long p =
                        ((unsigned long long)f2key(s) << 32) | (unsigned int)kc;
                    best[r] = p < best[r] ? p : best[r];
                }
            }
        }
    }
    // reduce across tx (16 threads share each row), then merge k-splits atomically
    #pragma unroll
    for (int r = 0; r < 8; ++r) {
        unsigned long long b = best[r];
        #pragma unroll
        for (int m = 1; m <= 8; m <<= 1) {
            unsigned long long o = __shfl_xor(b, m, 64);
            b = o < b ? o : b;
        }
        if (tx == 0) atomicMin(&keys[r0 + ty * 8 + r], b);
    }
}

extern "C" __global__ void finalize_kernel(const float* __restrict__ lat,
                                           const float* __restrict__ cbk,
                                           const float* __restrict__ noise,
                                           const unsigned long long* __restrict__ keys,
                                           float* __restrict__ out) {
    const int row = blockIdx.x;
    const int c = threadIdx.x;
    const unsigned long long p = keys[row];
    const int id = (int)(unsigned int)(p & 0xFFFFFFFFull);
    const int off = (int)rintf(noise[row] * 0.5f);   // round half-even == jnp.round
    int idn = id + off;
    idn = idn < 0 ? 0 : (idn > K_CODES - 1 ? K_CODES - 1 : idn);
    const float x  = lat[(size_t)row * C_DIM + c];
    const float qd = cbk[(size_t)id  * C_DIM + c];
    const float qn = cbk[(size_t)idn * C_DIM + c];
    out[(size_t)row * C_DIM + c] = x + (qn - x);     // ST forward value
    const float d1 = x - qd;
    const float d2 = qn - x;
    float t = (0.25f * d1 * d1 + d2 * d2) * (1.0f / 4194304.0f);
    #pragma unroll
    for (int m = 32; m; m >>= 1) t += __shfl_xor(t, m, 64);
    __shared__ float red[4];
    if ((c & 63) == 0) red[c >> 6] = t;
    __syncthreads();
    if (c == 0) {
        atomicAdd(out + (size_t)N_ROWS * C_DIM, red[0] + red[1] + red[2] + red[3]);
        out[(size_t)N_ROWS * C_DIM + 1 + row] = (float)idn;
    }
}

extern "C" void kernel_launch(void* const* d_in, const int* in_sizes, int n_in,
                              void* d_out, int out_size, void* d_ws, size_t ws_size,
                              hipStream_t stream) {
    const float* lat   = (const float*)d_in[0];
    const float* cbk   = (const float*)d_in[1];
    const float* noise = (const float*)d_in[2];
    float* out = (float*)d_out;

    float* wnorm = (float*)d_ws;                                   // 8192 f32
    unsigned long long* keys =
        (unsigned long long*)((char*)d_ws + K_CODES * sizeof(float)); // 16384 u64

    hipMemsetAsync(keys, 0xFF, (size_t)N_ROWS * sizeof(unsigned long long), stream);
    hipMemsetAsync(out + (size_t)N_ROWS * C_DIM, 0, sizeof(float), stream);

    wnorm_kernel<<<K_CODES / 4, 256, 0, stream>>>(cbk, wnorm);
    argmin_kernel<<<(N_ROWS / BM) * KSPLIT, 256, 0, stream>>>(lat, cbk, wnorm, keys);
    finalize_kernel<<<N_ROWS, 256, 0, stream>>>(lat, cbk, noise, keys, out);
}